// Round 13
// baseline (311.234 us; speedup 1.0000x reference)
//
#include <hip/hip_runtime.h>
#include <hip/hip_bf16.h>

#define NN 100000
#define EE 800000
#define HH 4
#define CC 64
#define GG 2000
#define NB 98           // scan blocks: ceil((NN/4)/256)

typedef unsigned short ushortx;
typedef __attribute__((ext_vector_type(8))) short short8;
typedef __attribute__((ext_vector_type(4))) float f32x4;

// ---------------- CSR build ----------------
// hist: atomicAdd's RETURN is the edge's within-dst rank -- store it
// (coalesced). fill then needs NO atomic: p = off[d] + rank[e].

__global__ void hist_kernel(const int* __restrict__ ei, int* __restrict__ deg,
                            int* __restrict__ rank) {
    int e = blockIdx.x * 256 + threadIdx.x;
    const int tot = EE + NN;
    if (e < tot) {
        int d = (e < EE) ? ei[EE + e] : (e - EE);
        rank[e] = atomicAdd(&deg[d], 1);
    }
}

__global__ __launch_bounds__(256) void scan_blk(const int* __restrict__ deg,
                                                int* __restrict__ bsum) {
    const int t = threadIdx.x;
    const int idx4 = blockIdx.x * 256 + t;
    int4 v = {0, 0, 0, 0};
    if (idx4 < NN / 4) v = ((const int4*)deg)[idx4];
    int s = v.x + v.y + v.z + v.w;
#pragma unroll
    for (int m = 32; m; m >>= 1) s += __shfl_xor(s, m, 64);
    __shared__ int ws[4];
    if ((t & 63) == 0) ws[t >> 6] = s;
    __syncthreads();
    if (t == 0) bsum[blockIdx.x] = ws[0] + ws[1] + ws[2] + ws[3];
}

__global__ void scan_mid(const int* __restrict__ bsum, int* __restrict__ boff,
                         int* __restrict__ off) {
    __shared__ int sh[128];
    const int t = threadIdx.x;
    int v = (t < NB) ? bsum[t] : 0;
    sh[t] = v;
    __syncthreads();
    for (int d = 1; d < 128; d <<= 1) {
        int u = (t >= d) ? sh[t - d] : 0;
        __syncthreads();
        sh[t] += u;
        __syncthreads();
    }
    if (t < NB) boff[t] = sh[t] - v;
    if (t == NB - 1) off[NN] = sh[t];
}

__global__ __launch_bounds__(256) void scan_fin(const int* __restrict__ deg,
                                                const int* __restrict__ boff,
                                                int* __restrict__ off) {
    const int t = threadIdx.x;
    const int idx4 = blockIdx.x * 256 + t;
    int4 v = {0, 0, 0, 0};
    if (idx4 < NN / 4) v = ((const int4*)deg)[idx4];
    int s = v.x + v.y + v.z + v.w;
    const int lane = t & 63, w = t >> 6;
    int inc = s;
#pragma unroll
    for (int d = 1; d < 64; d <<= 1) {
        int u = __shfl_up(inc, d, 64);
        if (lane >= d) inc += u;
    }
    __shared__ int ws[4];
    if (lane == 63) ws[w] = inc;
    __syncthreads();
    int woff = 0;
    for (int i = 0; i < w; ++i) woff += ws[i];
    int excl = inc - s + woff + boff[blockIdx.x];
    if (idx4 < NN / 4) {
        int4 o;
        o.x = excl;
        o.y = o.x + v.x;
        o.z = o.y + v.y;
        o.w = o.z + v.z;
        ((int4*)off)[idx4] = o;
    }
}

// XCD-sharded fill (R5-proven): no atomics, contiguous per-shard writes.
__global__ __launch_bounds__(256) void fill_sharded(
    const int* __restrict__ ei, const int* __restrict__ off,
    const int* __restrict__ rank, int* __restrict__ csr_src) {
    const int shard = blockIdx.x & 7;
    const int wblk = blockIdx.x >> 3;
    const int lo = shard * (NN / 8);
    const int hi = lo + (NN / 8);
    const int tot = EE + NN;
    for (int e = wblk * 256 + threadIdx.x; e < tot; e += 256 * 256) {
        int d = (e < EE) ? ei[EE + e] : (e - EE);
        if (d >= lo && d < hi) {
            int s = (e < EE) ? ei[e] : (e - EE);
            csr_src[off[d] + rank[e]] = s;
        }
    }
}

__device__ __forceinline__ ushortx f2bf(float v) {
    __hip_bfloat16 b = __float2bfloat16(v);
    return *reinterpret_cast<ushortx*>(&b);
}

// ---------------- parameter precompute (single merged kernel) ---------------

__device__ __forceinline__ void do_va(const float* __restrict__ W,
                                      const float* __restrict__ as_,
                                      const float* __restrict__ ad_,
                                      float* __restrict__ va, int K, int id) {
    if (id >= K * 8) return;
    int k = id >> 3, comp = id & 7;
    int h = comp & 3, sd = comp >> 2;
    const float* a = sd ? ad_ : as_;
    const float* wrow = W + k * 256 + h * 64;
    const float* arow = a + h * 64;
    float s = 0.f;
    for (int c = 0; c < 64; ++c) s = fmaf(wrow[c], arow[c], s);
    va[k * 8 + comp] = s;
}

__device__ __forceinline__ void do_wfrag(const float* __restrict__ W,
                                         ushortx* __restrict__ wfrag, int i) {
    if (i >= 16384) return;
    int j = i & 7, lane = (i >> 3) & 63, kb = (i >> 9) & 7, ct = i >> 12;
    int c = ct * 16 + (lane & 15);
    int kap = kb * 32 + (lane >> 4) * 8 + j;
    int h = kap >> 6, kw = kap & 63;
    wfrag[i] = f2bf(W[kw * 256 + h * 64 + c] * 0.25f);
}

__global__ void prep_all(
    const float* __restrict__ W1, const float* __restrict__ as1,
    const float* __restrict__ ad1, const float* __restrict__ W2,
    const float* __restrict__ as2, const float* __restrict__ ad2,
    const float* __restrict__ W3, const float* __restrict__ as3,
    const float* __restrict__ ad3, float* __restrict__ va1,
    float* __restrict__ va2, float* __restrict__ va3,
    ushortx* __restrict__ wf2, ushortx* __restrict__ wf3) {
    const int b = blockIdx.x, tid = threadIdx.x;
    if (b == 0) do_va(W1, as1, ad1, va1, 9, tid);
    else if (b <= 2) do_va(W2, as2, ad2, va2, 64, (b - 1) * 256 + tid);
    else if (b <= 4) do_va(W3, as3, ad3, va3, 64, (b - 3) * 256 + tid);
    else if (b <= 68) do_wfrag(W2, wf2, (b - 5) * 256 + tid);
    else do_wfrag(W3, wf3, (b - 69) * 256 + tid);
}

// ALS/ALD from fp32 X (layer 1, K=9).
template <int K>
__global__ __launch_bounds__(256) void att_gemv(
    const float* __restrict__ X, const float* __restrict__ va,
    float* __restrict__ ALS, float* __restrict__ ALD) {
    __shared__ float vs[K][8];
    const int tid = threadIdx.x;
    for (int i = tid; i < K * 8; i += 256) vs[i >> 3][i & 7] = va[i];
    __syncthreads();
    int n = blockIdx.x * 256 + tid;
    if (n >= NN) return;
    const float* xp = X + (size_t)n * K;
    float s0 = 0, s1 = 0, s2 = 0, s3 = 0, d0 = 0, d1 = 0, d2 = 0, d3 = 0;
#pragma unroll
    for (int k = 0; k < K; ++k) {
        float x1 = xp[k];
        const float4 vsv = *(const float4*)&vs[k][0];
        const float4 vdv = *(const float4*)&vs[k][4];
        s0 = fmaf(x1, vsv.x, s0); s1 = fmaf(x1, vsv.y, s1);
        s2 = fmaf(x1, vsv.z, s2); s3 = fmaf(x1, vsv.w, s3);
        d0 = fmaf(x1, vdv.x, d0); d1 = fmaf(x1, vdv.y, d1);
        d2 = fmaf(x1, vdv.z, d2); d3 = fmaf(x1, vdv.w, d3);
    }
    float4 so = {s0, s1, s2, s3}, dd = {d0, d1, d2, d3};
    ((float4*)ALS)[n] = so;
    ((float4*)ALD)[n] = dd;
}

// ALS/ALD from bf16 X (layers 2,3, K=64).
__global__ __launch_bounds__(256) void att_gemv_b(
    const ushortx* __restrict__ Xb, const float* __restrict__ va,
    float* __restrict__ ALS, float* __restrict__ ALD) {
    __shared__ float vs[64][8];
    const int tid = threadIdx.x;
    for (int i = tid; i < 64 * 8; i += 256) vs[i >> 3][i & 7] = va[i];
    __syncthreads();
    int n = blockIdx.x * 256 + tid;
    if (n >= NN) return;
    const uint4* xp = (const uint4*)(Xb + (size_t)n * 64);
    float s0 = 0, s1 = 0, s2 = 0, s3 = 0, d0 = 0, d1 = 0, d2 = 0, d3 = 0;
#pragma unroll
    for (int qq = 0; qq < 8; ++qq) {
        uint4 u = xp[qq];
        float xv[8];
        xv[0] = __uint_as_float(u.x << 16);
        xv[1] = __uint_as_float(u.x & 0xFFFF0000u);
        xv[2] = __uint_as_float(u.y << 16);
        xv[3] = __uint_as_float(u.y & 0xFFFF0000u);
        xv[4] = __uint_as_float(u.z << 16);
        xv[5] = __uint_as_float(u.z & 0xFFFF0000u);
        xv[6] = __uint_as_float(u.w << 16);
        xv[7] = __uint_as_float(u.w & 0xFFFF0000u);
#pragma unroll
        for (int j = 0; j < 8; ++j) {
            const int k = qq * 8 + j;
            const float4 vsv = *(const float4*)&vs[k][0];
            const float4 vdv = *(const float4*)&vs[k][4];
            s0 = fmaf(xv[j], vsv.x, s0); s1 = fmaf(xv[j], vsv.y, s1);
            s2 = fmaf(xv[j], vsv.z, s2); s3 = fmaf(xv[j], vsv.w, s3);
            d0 = fmaf(xv[j], vdv.x, d0); d1 = fmaf(xv[j], vdv.y, d1);
            d2 = fmaf(xv[j], vdv.z, d2); d3 = fmaf(xv[j], vdv.w, d3);
        }
    }
    float4 so = {s0, s1, s2, s3}, dd = {d0, d1, d2, d3};
    ((float4*)ALS)[n] = so;
    ((float4*)ALD)[n] = dd;
}

// ------------- shared weight-phase helper (leaky + exp, per lane) ----------
__device__ __forceinline__ float4 edge_w4(const float4 a, const float4 aldv) {
    float vx = a.x + aldv.x, vy = a.y + aldv.y,
          vz = a.z + aldv.z, vw = a.w + aldv.w;
    vx = (vx >= 0.f) ? vx : 0.2f * vx;
    vy = (vy >= 0.f) ? vy : 0.2f * vy;
    vz = (vz >= 0.f) ? vz : 0.2f * vz;
    vw = (vw >= 0.f) ? vw : 0.2f * vw;
    float4 w;
    w.x = __expf(vx); w.y = __expf(vy); w.z = __expf(vz); w.w = __expf(vw);
    return w;
}

// ------ layer-1 FUSED: aggregate raw x (4 nodes/wave) + K=36 fp32 GEMM -----
// 8-deep marginal loop: 8 gathers issued back-to-back before consumption
// (latency hiding). LDS table always has 16 written slots/chunk with
// zero-weight padding, so 8-slot strides are numerically exact.

__global__ __launch_bounds__(256) void agg_gemm1(
    const float* __restrict__ X, const float* __restrict__ ALS,
    const float* __restrict__ ALD, const int* __restrict__ off,
    const int* __restrict__ csr_src, const float* __restrict__ W1,
    const float* __restrict__ b1, ushortx* __restrict__ Xb) {
    __shared__ float4 wtab4[4][4][21];   // [wave][group][slot pad21]
    __shared__ int    svtab[4][4][21];
    __shared__ float  sX[16][40];        // 16 rows x 36 (+pad) fp32
    const int wv = threadIdx.x >> 6;
    const int l = threadIdx.x & 63;
    const int g = l >> 4, kg = l & 15;
    const int node = blockIdx.x * 16 + wv * 4 + g;
    const bool act = (kg < 9);
    const int beg = off[node], end = off[node + 1];
    int md = end - beg;
    md = max(md, __shfl_xor(md, 16, 64));
    md = max(md, __shfl_xor(md, 32, 64));
    const float4 aldv = ((const float4*)ALD)[node];
    const float4* wt = &wtab4[wv][g][0];
    const int* st = &svtab[wv][g][0];
    float4 acc = {0.f, 0.f, 0.f, 0.f};       // 4 heads, channel kg
    float4 den4 = {0.f, 0.f, 0.f, 0.f};

#define UPD1(vv, ww)                                                   \
    {                                                                  \
        acc.x = fmaf((ww).x, (vv), acc.x);                             \
        acc.y = fmaf((ww).y, (vv), acc.y);                             \
        acc.z = fmaf((ww).z, (vv), acc.z);                             \
        acc.w = fmaf((ww).w, (vv), acc.w);                             \
    }

    for (int c0 = 0; c0 < md; c0 += 16) {
        const int jj = beg + c0 + kg;
        int sv = 0;
        float4 w4 = {0.f, 0.f, 0.f, 0.f};
        if (jj < end) {
            sv = csr_src[jj];
            w4 = edge_w4(((const float4*)ALS)[sv], aldv);
        }
        den4.x += w4.x; den4.y += w4.y; den4.z += w4.z; den4.w += w4.w;
        wtab4[wv][g][kg] = w4;
        svtab[wv][g][kg] = sv;
        __builtin_amdgcn_wave_barrier();
        asm volatile("s_waitcnt lgkmcnt(0)" ::: "memory");
        __builtin_amdgcn_sched_barrier(0);

        const int mc = min(16, md - c0);
        for (int t = 0; t < mc; t += 8) {
            float4 wA = wt[t + 0]; int sA = st[t + 0];
            float4 wB = wt[t + 1]; int sB = st[t + 1];
            float4 wC = wt[t + 2]; int sC = st[t + 2];
            float4 wD = wt[t + 3]; int sD = st[t + 3];
            float4 wE = wt[t + 4]; int sE = st[t + 4];
            float4 wF = wt[t + 5]; int sF = st[t + 5];
            float4 wG = wt[t + 6]; int sG = st[t + 6];
            float4 wH = wt[t + 7]; int sH = st[t + 7];
            float vA = 0.f, vB = 0.f, vC = 0.f, vD = 0.f;
            float vE = 0.f, vF = 0.f, vG = 0.f, vH = 0.f;
            if (act) {
                vA = X[(size_t)sA * 9 + kg];
                vB = X[(size_t)sB * 9 + kg];
                vC = X[(size_t)sC * 9 + kg];
                vD = X[(size_t)sD * 9 + kg];
                vE = X[(size_t)sE * 9 + kg];
                vF = X[(size_t)sF * 9 + kg];
                vG = X[(size_t)sG * 9 + kg];
                vH = X[(size_t)sH * 9 + kg];
            }
            UPD1(vA, wA); UPD1(vB, wB); UPD1(vC, wC); UPD1(vD, wD);
            UPD1(vE, wE); UPD1(vF, wF); UPD1(vG, wG); UPD1(vH, wH);
        }
        __builtin_amdgcn_wave_barrier();
    }
#undef UPD1

#pragma unroll
    for (int m = 1; m <= 8; m <<= 1) {
        den4.x += __shfl_xor(den4.x, m, 64);
        den4.y += __shfl_xor(den4.y, m, 64);
        den4.z += __shfl_xor(den4.z, m, 64);
        den4.w += __shfl_xor(den4.w, m, 64);
    }
    if (act) {
        float i0 = 1.f / (den4.x + 1e-16f);
        float i1 = 1.f / (den4.y + 1e-16f);
        float i2 = 1.f / (den4.z + 1e-16f);
        float i3 = 1.f / (den4.w + 1e-16f);
        float* o = &sX[wv * 4 + g][0];
        o[0 * 9 + kg] = acc.x * i0;
        o[1 * 9 + kg] = acc.y * i1;
        o[2 * 9 + kg] = acc.z * i2;
        o[3 * 9 + kg] = acc.w * i3;
    }
    __syncthreads();

    // ---- GEMM phase: wave wv handles rows wv*4..+3, lane l = channel ----
    const int c = l;
    float wreg[36];
#pragma unroll
    for (int h = 0; h < 4; ++h)
#pragma unroll
        for (int k = 0; k < 9; ++k)
            wreg[h * 9 + k] = W1[k * 256 + h * 64 + c] * 0.25f;
    const float bc = b1[c];
#pragma unroll
    for (int r = 0; r < 4; ++r) {
        const int row = wv * 4 + r;
        float s = 0.f;
#pragma unroll
        for (int i4 = 0; i4 < 9; ++i4) {
            const float4 xv = *(const float4*)&sX[row][i4 * 4];
            s = fmaf(wreg[i4 * 4 + 0], xv.x, s);
            s = fmaf(wreg[i4 * 4 + 1], xv.y, s);
            s = fmaf(wreg[i4 * 4 + 2], xv.z, s);
            s = fmaf(wreg[i4 * 4 + 3], xv.w, s);
        }
        s = fmaxf(s + bc, 0.f);
        Xb[(size_t)(blockIdx.x * 16 + row) * 64 + c] = f2bf(s);
    }
}

// ------- layers 2,3 FUSED: aggregate (4 nodes/wave) + K=256 MFMA GEMM ------
// 8-deep marginal loop (8 gathers in flight). Zero-weight padded slots keep
// 8-slot strides exact. MFMA phase identical to the verified R11 version.

template <bool F32OUT>
__global__ __launch_bounds__(256) void agg_gemm(
    const ushortx* __restrict__ Xb, const float* __restrict__ ALS,
    const float* __restrict__ ALD, const int* __restrict__ off,
    const int* __restrict__ csr_src, const ushortx* __restrict__ wfrag,
    const float* __restrict__ bias, ushortx* __restrict__ XbOut,
    float* __restrict__ OUTF) {
    __shared__ float4 wtab4[4][4][21];   // [wave][group][slot pad21]
    __shared__ int    svtab[4][4][21];
    __shared__ ushortx sAgg[16][264];    // 16 rows x 528B pitch (8.25 KB)
    const int wv = threadIdx.x >> 6;
    const int l = threadIdx.x & 63;
    const int g = l >> 4, c4 = l & 15;
    const int node = blockIdx.x * 16 + wv * 4 + g;
    const int beg = off[node], end = off[node + 1];
    int md = end - beg;
    md = max(md, __shfl_xor(md, 16, 64));
    md = max(md, __shfl_xor(md, 32, 64));
    const float4 aldv = ((const float4*)ALD)[node];
    const uint2* xb2 = (const uint2*)Xb;   // row = 16 uint2 (64 bf16)
    const float4* wt = &wtab4[wv][g][0];
    const int* st = &svtab[wv][g][0];
    float4 a0 = {0.f, 0.f, 0.f, 0.f};      // head 0, ch c4*4..+3
    float4 a1 = {0.f, 0.f, 0.f, 0.f};
    float4 a2 = {0.f, 0.f, 0.f, 0.f};
    float4 a3 = {0.f, 0.f, 0.f, 0.f};
    float4 den4 = {0.f, 0.f, 0.f, 0.f};

#define UPD(uu, ww)                                                 \
    {                                                               \
        float c0v = __uint_as_float((uu).x << 16);                  \
        float c1v = __uint_as_float((uu).x & 0xFFFF0000u);          \
        float c2v = __uint_as_float((uu).y << 16);                  \
        float c3v = __uint_as_float((uu).y & 0xFFFF0000u);          \
        a0.x = fmaf((ww).x, c0v, a0.x); a0.y = fmaf((ww).x, c1v, a0.y); \
        a0.z = fmaf((ww).x, c2v, a0.z); a0.w = fmaf((ww).x, c3v, a0.w); \
        a1.x = fmaf((ww).y, c0v, a1.x); a1.y = fmaf((ww).y, c1v, a1.y); \
        a1.z = fmaf((ww).y, c2v, a1.z); a1.w = fmaf((ww).y, c3v, a1.w); \
        a2.x = fmaf((ww).z, c0v, a2.x); a2.y = fmaf((ww).z, c1v, a2.y); \
        a2.z = fmaf((ww).z, c2v, a2.z); a2.w = fmaf((ww).z, c3v, a2.w); \
        a3.x = fmaf((ww).w, c0v, a3.x); a3.y = fmaf((ww).w, c1v, a3.y); \
        a3.z = fmaf((ww).w, c2v, a3.z); a3.w = fmaf((ww).w, c3v, a3.w); \
    }

    for (int c0 = 0; c0 < md; c0 += 16) {
        const int jj = beg + c0 + c4;
        int sv = 0;
        float4 w4 = {0.f, 0.f, 0.f, 0.f};
        if (jj < end) {
            sv = csr_src[jj];
            w4 = edge_w4(((const float4*)ALS)[sv], aldv);
        }
        den4.x += w4.x; den4.y += w4.y; den4.z += w4.z; den4.w += w4.w;
        wtab4[wv][g][c4] = w4;
        svtab[wv][g][c4] = sv;
        __builtin_amdgcn_wave_barrier();
        asm volatile("s_waitcnt lgkmcnt(0)" ::: "memory");
        __builtin_amdgcn_sched_barrier(0);

        const int mc = min(16, md - c0);
        for (int t = 0; t < mc; t += 8) {
            float4 wA = wt[t + 0]; int sA = st[t + 0];
            float4 wB = wt[t + 1]; int sB = st[t + 1];
            float4 wC = wt[t + 2]; int sC = st[t + 2];
            float4 wD = wt[t + 3]; int sD = st[t + 3];
            float4 wE = wt[t + 4]; int sE = st[t + 4];
            float4 wF = wt[t + 5]; int sF = st[t + 5];
            float4 wG = wt[t + 6]; int sG = st[t + 6];
            float4 wH = wt[t + 7]; int sH = st[t + 7];
            uint2 uA = xb2[(size_t)sA * 16 + c4];
            uint2 uB = xb2[(size_t)sB * 16 + c4];
            uint2 uC = xb2[(size_t)sC * 16 + c4];
            uint2 uD = xb2[(size_t)sD * 16 + c4];
            uint2 uE = xb2[(size_t)sE * 16 + c4];
            uint2 uF = xb2[(size_t)sF * 16 + c4];
            uint2 uG = xb2[(size_t)sG * 16 + c4];
            uint2 uH = xb2[(size_t)sH * 16 + c4];
            UPD(uA, wA);
            UPD(uB, wB);
            UPD(uC, wC);
            UPD(uD, wD);
            UPD(uE, wE);
            UPD(uF, wF);
            UPD(uG, wG);
            UPD(uH, wH);
        }
        __builtin_amdgcn_wave_barrier();
    }
#undef UPD

#pragma unroll
    for (int m = 1; m <= 8; m <<= 1) {
        den4.x += __shfl_xor(den4.x, m, 64);
        den4.y += __shfl_xor(den4.y, m, 64);
        den4.z += __shfl_xor(den4.z, m, 64);
        den4.w += __shfl_xor(den4.w, m, 64);
    }
    {
        float i0 = 1.f / (den4.x + 1e-16f);
        float i1 = 1.f / (den4.y + 1e-16f);
        float i2 = 1.f / (den4.z + 1e-16f);
        float i3 = 1.f / (den4.w + 1e-16f);
        ushortx* orow = &sAgg[wv * 4 + g][0];
        uint p0, p1;
        p0 = (uint)f2bf(a0.x * i0) | ((uint)f2bf(a0.y * i0) << 16);
        p1 = (uint)f2bf(a0.z * i0) | ((uint)f2bf(a0.w * i0) << 16);
        *(uint2*)&orow[0 * 64 + c4 * 4] = uint2{p0, p1};
        p0 = (uint)f2bf(a1.x * i1) | ((uint)f2bf(a1.y * i1) << 16);
        p1 = (uint)f2bf(a1.z * i1) | ((uint)f2bf(a1.w * i1) << 16);
        *(uint2*)&orow[1 * 64 + c4 * 4] = uint2{p0, p1};
        p0 = (uint)f2bf(a2.x * i2) | ((uint)f2bf(a2.y * i2) << 16);
        p1 = (uint)f2bf(a2.z * i2) | ((uint)f2bf(a2.w * i2) << 16);
        *(uint2*)&orow[2 * 64 + c4 * 4] = uint2{p0, p1};
        p0 = (uint)f2bf(a3.x * i3) | ((uint)f2bf(a3.y * i3) << 16);
        p1 = (uint)f2bf(a3.z * i3) | ((uint)f2bf(a3.w * i3) << 16);
        *(uint2*)&orow[3 * 64 + c4 * 4] = uint2{p0, p1};
    }
    __syncthreads();

    // ---- MFMA phase: wave wv computes column-tile ct = wv ----
    const int n = l & 15, q = l >> 4;
    f32x4 acc = {0.f, 0.f, 0.f, 0.f};
#pragma unroll
    for (int kb = 0; kb < 8; ++kb) {
        short8 a = *(const short8*)&sAgg[n][kb * 32 + q * 8];
        short8 b = *(const short8*)&wfrag[(size_t)((wv * 8 + kb) * 64 + l) * 8];
        acc = __builtin_amdgcn_mfma_f32_16x16x32_bf16(b, a, acc, 0, 0, 0);
    }
    const int row = blockIdx.x * 16 + n;
    const int col = wv * 16 + q * 4;
    float4 b4 = ((const float4*)bias)[wv * 4 + q];
    float o0 = fmaxf(acc[0] + b4.x, 0.f);
    float o1 = fmaxf(acc[1] + b4.y, 0.f);
    float o2 = fmaxf(acc[2] + b4.z, 0.f);
    float o3 = fmaxf(acc[3] + b4.w, 0.f);
    if constexpr (F32OUT) {
        float4 ov = {o0, o1, o2, o3};
        *(float4*)&OUTF[(size_t)row * 64 + col] = ov;
    } else {
        uint p0 = (uint)f2bf(o0) | ((uint)f2bf(o1) << 16);
        uint p1 = (uint)f2bf(o2) | ((uint)f2bf(o3) << 16);
        uint2 ov = {p0, p1};
        *(uint2*)&XbOut[(size_t)row * 64 + col] = ov;
    }
}

// ---------------- graph mean-pool + final linear (no atomics) --------------

__global__ __launch_bounds__(256) void pool_graph(
    const float* __restrict__ OUTF, const int* __restrict__ batch,
    const float* __restrict__ lw, const float* __restrict__ lb,
    float* __restrict__ out) {
    const int g = blockIdx.x * 4 + (threadIdx.x >> 6);
    const int l = threadIdx.x & 63;
    if (g >= GG) return;
    int lo = 0, hi = NN;
    while (lo < hi) { int mid = (lo + hi) >> 1; if (batch[mid] < g) lo = mid + 1; else hi = mid; }
    int lo2 = lo, hi2 = NN;
    while (lo2 < hi2) { int mid = (lo2 + hi2) >> 1; if (batch[mid] < g + 1) lo2 = mid + 1; else hi2 = mid; }
    float s = 0.f;
    int nn = lo;
    for (; nn + 4 <= lo2; nn += 4) {
        float a0 = OUTF[(size_t)(nn + 0) * 64 + l];
        float a1 = OUTF[(size_t)(nn + 1) * 64 + l];
        float a2 = OUTF[(size_t)(nn + 2) * 64 + l];
        float a3 = OUTF[(size_t)(nn + 3) * 64 + l];
        s += (a0 + a1) + (a2 + a3);
    }
    for (; nn < lo2; ++nn) s += OUTF[(size_t)nn * 64 + l];
    const float cntf = fmaxf((float)(lo2 - lo), 1.f);
    float v = s / cntf * lw[l];
#pragma unroll
    for (int m = 32; m; m >>= 1) v += __shfl_xor(v, m, 64);
    if (l == 0) out[g] = v + lb[0];
}

// ---------------- launch ----------------

extern "C" void kernel_launch(void* const* d_in, const int* in_sizes, int n_in,
                              void* d_out, int out_size, void* d_ws, size_t ws_size,
                              hipStream_t stream) {
    const float* x     = (const float*)d_in[0];
    const int*   ei    = (const int*)d_in[1];
    const int*   batch = (const int*)d_in[2];
    const float* W1  = (const float*)d_in[3];
    const float* as1 = (const float*)d_in[4];
    const float* ad1 = (const float*)d_in[5];
    const float* b1  = (const float*)d_in[6];
    const float* W2  = (const float*)d_in[7];
    const float* as2 = (const float*)d_in[8];
    const float* ad2 = (const float*)d_in[9];
    const float* b2  = (const float*)d_in[10];
    const float* W3  = (const float*)d_in[11];
    const float* as3 = (const float*)d_in[12];
    const float* ad3 = (const float*)d_in[13];
    const float* b3  = (const float*)d_in[14];
    const float* lw  = (const float*)d_in[15];
    const float* lb  = (const float*)d_in[16];
    float* out = (float*)d_out;

    char* p = (char*)d_ws;
    auto carve = [&](size_t bytes) -> void* {
        void* r = (void*)p;
        p += (bytes + 255) & ~(size_t)255;
        return r;
    };
    int*     off    = (int*)carve((NN + 4) * sizeof(int));
    int*     deg    = (int*)carve(NN * sizeof(int));
    int*     rank   = (int*)carve((size_t)(EE + NN) * sizeof(int));
    int*     bsum   = (int*)carve(NB * sizeof(int));
    int*     boff   = (int*)carve(NB * sizeof(int));
    int*     csr    = (int*)carve((size_t)(EE + NN) * sizeof(int));
    ushortx* xb1    = (ushortx*)carve((size_t)NN * 64 * sizeof(ushortx));   // 12.8 MB
    ushortx* xb2    = (ushortx*)carve((size_t)NN * 64 * sizeof(ushortx));   // 12.8 MB
    float*   outf   = (float*)carve((size_t)NN * 64 * sizeof(float));       // 25.6 MB
    float*   als    = (float*)carve((size_t)NN * 4 * sizeof(float));
    float*   ald    = (float*)carve((size_t)NN * 4 * sizeof(float));
    float*   va1    = (float*)carve(9 * 8 * sizeof(float));
    float*   va2    = (float*)carve(64 * 8 * sizeof(float));
    float*   va3    = (float*)carve(64 * 8 * sizeof(float));
    ushortx* wf2    = (ushortx*)carve(16384 * sizeof(ushortx));
    ushortx* wf3    = (ushortx*)carve(16384 * sizeof(ushortx));

    hipMemsetAsync(deg, 0, NN * sizeof(int), stream);

    const int etot = EE + NN;
    const int eblocks = (etot + 255) / 256;
    hist_kernel<<<eblocks, 256, 0, stream>>>(ei, deg, rank);
    scan_blk<<<NB, 256, 0, stream>>>(deg, bsum);
    scan_mid<<<1, 128, 0, stream>>>(bsum, boff, off);
    scan_fin<<<NB, 256, 0, stream>>>(deg, boff, off);
    fill_sharded<<<2048, 256, 0, stream>>>(ei, off, rank, csr);

    prep_all<<<133, 256, 0, stream>>>(W1, as1, ad1, W2, as2, ad2, W3, as3, ad3,
                                      va1, va2, va3, wf2, wf3);

    const int ablocks = NN / 16;           // 6250: 4 nodes/wave, 4 waves/block
    const int nblocks = (NN + 255) / 256;

    // layer 1 (fused fp32 aggregate + K=36 GEMM)
    att_gemv<9><<<nblocks, 256, 0, stream>>>(x, va1, als, ald);
    agg_gemm1<<<ablocks, 256, 0, stream>>>(x, als, ald, off, csr, W1, b1, xb1);

    // layer 2 (fused aggregate + MFMA GEMM)
    att_gemv_b<<<nblocks, 256, 0, stream>>>(xb1, va2, als, ald);
    agg_gemm<false><<<ablocks, 256, 0, stream>>>(xb1, als, ald, off, csr, wf2,
                                                 b2, xb2, nullptr);

    // layer 3 (fused; fp32 node outputs, pooling in dedicated kernel)
    att_gemv_b<<<nblocks, 256, 0, stream>>>(xb2, va3, als, ald);
    agg_gemm<true><<<ablocks, 256, 0, stream>>>(xb2, als, ald, off, csr, wf3,
                                                b3, nullptr, outf);

    pool_graph<<<(GG + 3) / 4, 256, 0, stream>>>(outf, batch, lw, lb, out);
}

// Round 14
// 288.511 us; speedup vs baseline: 1.0788x; 1.0788x over previous
//
#include <hip/hip_runtime.h>
#include <hip/hip_bf16.h>

#define NN 100000
#define EE 800000
#define HH 4
#define CC 64
#define GG 2000
#define NB 98           // scan blocks: ceil((NN/4)/256)

typedef unsigned short ushortx;
typedef __attribute__((ext_vector_type(8))) short short8;
typedef __attribute__((ext_vector_type(4))) float f32x4;

// ---------------- CSR build ----------------
// hist: atomicAdd's RETURN is the edge's within-dst rank -- store it
// (coalesced). fill then needs NO atomic: p = off[d] + rank[e].

__global__ void hist_kernel(const int* __restrict__ ei, int* __restrict__ deg,
                            int* __restrict__ rank) {
    int e = blockIdx.x * 256 + threadIdx.x;
    const int tot = EE + NN;
    if (e < tot) {
        int d = (e < EE) ? ei[EE + e] : (e - EE);
        rank[e] = atomicAdd(&deg[d], 1);
    }
}

__global__ __launch_bounds__(256) void scan_blk(const int* __restrict__ deg,
                                                int* __restrict__ bsum) {
    const int t = threadIdx.x;
    const int idx4 = blockIdx.x * 256 + t;
    int4 v = {0, 0, 0, 0};
    if (idx4 < NN / 4) v = ((const int4*)deg)[idx4];
    int s = v.x + v.y + v.z + v.w;
#pragma unroll
    for (int m = 32; m; m >>= 1) s += __shfl_xor(s, m, 64);
    __shared__ int ws[4];
    if ((t & 63) == 0) ws[t >> 6] = s;
    __syncthreads();
    if (t == 0) bsum[blockIdx.x] = ws[0] + ws[1] + ws[2] + ws[3];
}

__global__ void scan_mid(const int* __restrict__ bsum, int* __restrict__ boff,
                         int* __restrict__ off) {
    __shared__ int sh[128];
    const int t = threadIdx.x;
    int v = (t < NB) ? bsum[t] : 0;
    sh[t] = v;
    __syncthreads();
    for (int d = 1; d < 128; d <<= 1) {
        int u = (t >= d) ? sh[t - d] : 0;
        __syncthreads();
        sh[t] += u;
        __syncthreads();
    }
    if (t < NB) boff[t] = sh[t] - v;
    if (t == NB - 1) off[NN] = sh[t];
}

__global__ __launch_bounds__(256) void scan_fin(const int* __restrict__ deg,
                                                const int* __restrict__ boff,
                                                int* __restrict__ off) {
    const int t = threadIdx.x;
    const int idx4 = blockIdx.x * 256 + t;
    int4 v = {0, 0, 0, 0};
    if (idx4 < NN / 4) v = ((const int4*)deg)[idx4];
    int s = v.x + v.y + v.z + v.w;
    const int lane = t & 63, w = t >> 6;
    int inc = s;
#pragma unroll
    for (int d = 1; d < 64; d <<= 1) {
        int u = __shfl_up(inc, d, 64);
        if (lane >= d) inc += u;
    }
    __shared__ int ws[4];
    if (lane == 63) ws[w] = inc;
    __syncthreads();
    int woff = 0;
    for (int i = 0; i < w; ++i) woff += ws[i];
    int excl = inc - s + woff + boff[blockIdx.x];
    if (idx4 < NN / 4) {
        int4 o;
        o.x = excl;
        o.y = o.x + v.x;
        o.z = o.y + v.y;
        o.w = o.z + v.z;
        ((int4*)off)[idx4] = o;
    }
}

// XCD-sharded fill (R5-proven): no atomics, contiguous per-shard writes.
__global__ __launch_bounds__(256) void fill_sharded(
    const int* __restrict__ ei, const int* __restrict__ off,
    const int* __restrict__ rank, int* __restrict__ csr_src) {
    const int shard = blockIdx.x & 7;
    const int wblk = blockIdx.x >> 3;
    const int lo = shard * (NN / 8);
    const int hi = lo + (NN / 8);
    const int tot = EE + NN;
    for (int e = wblk * 256 + threadIdx.x; e < tot; e += 256 * 256) {
        int d = (e < EE) ? ei[EE + e] : (e - EE);
        if (d >= lo && d < hi) {
            int s = (e < EE) ? ei[e] : (e - EE);
            csr_src[off[d] + rank[e]] = s;
        }
    }
}

__device__ __forceinline__ ushortx f2bf(float v) {
    __hip_bfloat16 b = __float2bfloat16(v);
    return *reinterpret_cast<ushortx*>(&b);
}

// ---------------- parameter precompute (single merged kernel) ---------------

__device__ __forceinline__ void do_va(const float* __restrict__ W,
                                      const float* __restrict__ as_,
                                      const float* __restrict__ ad_,
                                      float* __restrict__ va, int K, int id) {
    if (id >= K * 8) return;
    int k = id >> 3, comp = id & 7;
    int h = comp & 3, sd = comp >> 2;
    const float* a = sd ? ad_ : as_;
    const float* wrow = W + k * 256 + h * 64;
    const float* arow = a + h * 64;
    float s = 0.f;
    for (int c = 0; c < 64; ++c) s = fmaf(wrow[c], arow[c], s);
    va[k * 8 + comp] = s;
}

__device__ __forceinline__ void do_wfrag(const float* __restrict__ W,
                                         ushortx* __restrict__ wfrag, int i) {
    if (i >= 16384) return;
    int j = i & 7, lane = (i >> 3) & 63, kb = (i >> 9) & 7, ct = i >> 12;
    int c = ct * 16 + (lane & 15);
    int kap = kb * 32 + (lane >> 4) * 8 + j;
    int h = kap >> 6, kw = kap & 63;
    wfrag[i] = f2bf(W[kw * 256 + h * 64 + c] * 0.25f);
}

__global__ void prep_all(
    const float* __restrict__ W1, const float* __restrict__ as1,
    const float* __restrict__ ad1, const float* __restrict__ W2,
    const float* __restrict__ as2, const float* __restrict__ ad2,
    const float* __restrict__ W3, const float* __restrict__ as3,
    const float* __restrict__ ad3, float* __restrict__ va1,
    float* __restrict__ va2, float* __restrict__ va3,
    ushortx* __restrict__ wf2, ushortx* __restrict__ wf3) {
    const int b = blockIdx.x, tid = threadIdx.x;
    if (b == 0) do_va(W1, as1, ad1, va1, 9, tid);
    else if (b <= 2) do_va(W2, as2, ad2, va2, 64, (b - 1) * 256 + tid);
    else if (b <= 4) do_va(W3, as3, ad3, va3, 64, (b - 3) * 256 + tid);
    else if (b <= 68) do_wfrag(W2, wf2, (b - 5) * 256 + tid);
    else do_wfrag(W3, wf3, (b - 69) * 256 + tid);
}

// ALS/ALD from fp32 X (layer 1, K=9).
template <int K>
__global__ __launch_bounds__(256) void att_gemv(
    const float* __restrict__ X, const float* __restrict__ va,
    float* __restrict__ ALS, float* __restrict__ ALD) {
    __shared__ float vs[K][8];
    const int tid = threadIdx.x;
    for (int i = tid; i < K * 8; i += 256) vs[i >> 3][i & 7] = va[i];
    __syncthreads();
    int n = blockIdx.x * 256 + tid;
    if (n >= NN) return;
    const float* xp = X + (size_t)n * K;
    float s0 = 0, s1 = 0, s2 = 0, s3 = 0, d0 = 0, d1 = 0, d2 = 0, d3 = 0;
#pragma unroll
    for (int k = 0; k < K; ++k) {
        float x1 = xp[k];
        const float4 vsv = *(const float4*)&vs[k][0];
        const float4 vdv = *(const float4*)&vs[k][4];
        s0 = fmaf(x1, vsv.x, s0); s1 = fmaf(x1, vsv.y, s1);
        s2 = fmaf(x1, vsv.z, s2); s3 = fmaf(x1, vsv.w, s3);
        d0 = fmaf(x1, vdv.x, d0); d1 = fmaf(x1, vdv.y, d1);
        d2 = fmaf(x1, vdv.z, d2); d3 = fmaf(x1, vdv.w, d3);
    }
    float4 so = {s0, s1, s2, s3}, dd = {d0, d1, d2, d3};
    ((float4*)ALS)[n] = so;
    ((float4*)ALD)[n] = dd;
}

// ALS/ALD from bf16 X (layers 2,3, K=64).
__global__ __launch_bounds__(256) void att_gemv_b(
    const ushortx* __restrict__ Xb, const float* __restrict__ va,
    float* __restrict__ ALS, float* __restrict__ ALD) {
    __shared__ float vs[64][8];
    const int tid = threadIdx.x;
    for (int i = tid; i < 64 * 8; i += 256) vs[i >> 3][i & 7] = va[i];
    __syncthreads();
    int n = blockIdx.x * 256 + tid;
    if (n >= NN) return;
    const uint4* xp = (const uint4*)(Xb + (size_t)n * 64);
    float s0 = 0, s1 = 0, s2 = 0, s3 = 0, d0 = 0, d1 = 0, d2 = 0, d3 = 0;
#pragma unroll
    for (int qq = 0; qq < 8; ++qq) {
        uint4 u = xp[qq];
        float xv[8];
        xv[0] = __uint_as_float(u.x << 16);
        xv[1] = __uint_as_float(u.x & 0xFFFF0000u);
        xv[2] = __uint_as_float(u.y << 16);
        xv[3] = __uint_as_float(u.y & 0xFFFF0000u);
        xv[4] = __uint_as_float(u.z << 16);
        xv[5] = __uint_as_float(u.z & 0xFFFF0000u);
        xv[6] = __uint_as_float(u.w << 16);
        xv[7] = __uint_as_float(u.w & 0xFFFF0000u);
#pragma unroll
        for (int j = 0; j < 8; ++j) {
            const int k = qq * 8 + j;
            const float4 vsv = *(const float4*)&vs[k][0];
            const float4 vdv = *(const float4*)&vs[k][4];
            s0 = fmaf(xv[j], vsv.x, s0); s1 = fmaf(xv[j], vsv.y, s1);
            s2 = fmaf(xv[j], vsv.z, s2); s3 = fmaf(xv[j], vsv.w, s3);
            d0 = fmaf(xv[j], vdv.x, d0); d1 = fmaf(xv[j], vdv.y, d1);
            d2 = fmaf(xv[j], vdv.z, d2); d3 = fmaf(xv[j], vdv.w, d3);
        }
    }
    float4 so = {s0, s1, s2, s3}, dd = {d0, d1, d2, d3};
    ((float4*)ALS)[n] = so;
    ((float4*)ALD)[n] = dd;
}

// ------------- shared weight-phase helper (leaky + exp, per lane) ----------
__device__ __forceinline__ float4 edge_w4(const float4 a, const float4 aldv) {
    float vx = a.x + aldv.x, vy = a.y + aldv.y,
          vz = a.z + aldv.z, vw = a.w + aldv.w;
    vx = (vx >= 0.f) ? vx : 0.2f * vx;
    vy = (vy >= 0.f) ? vy : 0.2f * vy;
    vz = (vz >= 0.f) ? vz : 0.2f * vz;
    vw = (vw >= 0.f) ? vw : 0.2f * vw;
    float4 w;
    w.x = __expf(vx); w.y = __expf(vy); w.z = __expf(vz); w.w = __expf(vw);
    return w;
}

// ------ layer-1 FUSED: aggregate raw x (4 nodes/wave) + K=36 fp32 GEMM -----
// (R12-proven, 4-deep marginal loop: keeps VGPR at ~48 -> occupancy 40%;
// R13 lesson: 8-deep raised VGPR to 68, cut occupancy to 27%, REGRESSED --
// TLP, not ILP, hides the gather latency here.)

__global__ __launch_bounds__(256) void agg_gemm1(
    const float* __restrict__ X, const float* __restrict__ ALS,
    const float* __restrict__ ALD, const int* __restrict__ off,
    const int* __restrict__ csr_src, const float* __restrict__ W1,
    const float* __restrict__ b1, ushortx* __restrict__ Xb) {
    __shared__ float4 wtab4[4][4][21];   // [wave][group][slot pad21]
    __shared__ int    svtab[4][4][21];
    __shared__ float  sX[16][40];        // 16 rows x 36 (+pad) fp32
    const int wv = threadIdx.x >> 6;
    const int l = threadIdx.x & 63;
    const int g = l >> 4, kg = l & 15;
    const int node = blockIdx.x * 16 + wv * 4 + g;
    const bool act = (kg < 9);
    const int beg = off[node], end = off[node + 1];
    int md = end - beg;
    md = max(md, __shfl_xor(md, 16, 64));
    md = max(md, __shfl_xor(md, 32, 64));
    const float4 aldv = ((const float4*)ALD)[node];
    const float4* wt = &wtab4[wv][g][0];
    const int* st = &svtab[wv][g][0];
    float4 acc = {0.f, 0.f, 0.f, 0.f};       // 4 heads, channel kg
    float4 den4 = {0.f, 0.f, 0.f, 0.f};

    for (int c0 = 0; c0 < md; c0 += 16) {
        const int jj = beg + c0 + kg;
        int sv = 0;
        float4 w4 = {0.f, 0.f, 0.f, 0.f};
        if (jj < end) {
            sv = csr_src[jj];
            w4 = edge_w4(((const float4*)ALS)[sv], aldv);
        }
        den4.x += w4.x; den4.y += w4.y; den4.z += w4.z; den4.w += w4.w;
        wtab4[wv][g][kg] = w4;
        svtab[wv][g][kg] = sv;
        __builtin_amdgcn_wave_barrier();
        asm volatile("s_waitcnt lgkmcnt(0)" ::: "memory");
        __builtin_amdgcn_sched_barrier(0);

        const int mc = min(16, md - c0);
        for (int t = 0; t < mc; t += 4) {
            float4 wA = wt[t + 0]; int sA = st[t + 0];
            float4 wB = wt[t + 1]; int sB = st[t + 1];
            float4 wC = wt[t + 2]; int sC = st[t + 2];
            float4 wD = wt[t + 3]; int sD = st[t + 3];
            float vA = 0.f, vB = 0.f, vC = 0.f, vD = 0.f;
            if (act) {
                vA = X[(size_t)sA * 9 + kg];
                vB = X[(size_t)sB * 9 + kg];
                vC = X[(size_t)sC * 9 + kg];
                vD = X[(size_t)sD * 9 + kg];
            }
            acc.x = fmaf(wA.x, vA, acc.x); acc.y = fmaf(wA.y, vA, acc.y);
            acc.z = fmaf(wA.z, vA, acc.z); acc.w = fmaf(wA.w, vA, acc.w);
            acc.x = fmaf(wB.x, vB, acc.x); acc.y = fmaf(wB.y, vB, acc.y);
            acc.z = fmaf(wB.z, vB, acc.z); acc.w = fmaf(wB.w, vB, acc.w);
            acc.x = fmaf(wC.x, vC, acc.x); acc.y = fmaf(wC.y, vC, acc.y);
            acc.z = fmaf(wC.z, vC, acc.z); acc.w = fmaf(wC.w, vC, acc.w);
            acc.x = fmaf(wD.x, vD, acc.x); acc.y = fmaf(wD.y, vD, acc.y);
            acc.z = fmaf(wD.z, vD, acc.z); acc.w = fmaf(wD.w, vD, acc.w);
        }
        __builtin_amdgcn_wave_barrier();
    }

#pragma unroll
    for (int m = 1; m <= 8; m <<= 1) {
        den4.x += __shfl_xor(den4.x, m, 64);
        den4.y += __shfl_xor(den4.y, m, 64);
        den4.z += __shfl_xor(den4.z, m, 64);
        den4.w += __shfl_xor(den4.w, m, 64);
    }
    if (act) {
        float i0 = 1.f / (den4.x + 1e-16f);
        float i1 = 1.f / (den4.y + 1e-16f);
        float i2 = 1.f / (den4.z + 1e-16f);
        float i3 = 1.f / (den4.w + 1e-16f);
        float* o = &sX[wv * 4 + g][0];
        o[0 * 9 + kg] = acc.x * i0;
        o[1 * 9 + kg] = acc.y * i1;
        o[2 * 9 + kg] = acc.z * i2;
        o[3 * 9 + kg] = acc.w * i3;
    }
    __syncthreads();

    // ---- GEMM phase: wave wv handles rows wv*4..+3, lane l = channel ----
    const int c = l;
    float wreg[36];
#pragma unroll
    for (int h = 0; h < 4; ++h)
#pragma unroll
        for (int k = 0; k < 9; ++k)
            wreg[h * 9 + k] = W1[k * 256 + h * 64 + c] * 0.25f;
    const float bc = b1[c];
#pragma unroll
    for (int r = 0; r < 4; ++r) {
        const int row = wv * 4 + r;
        float s = 0.f;
#pragma unroll
        for (int i4 = 0; i4 < 9; ++i4) {
            const float4 xv = *(const float4*)&sX[row][i4 * 4];
            s = fmaf(wreg[i4 * 4 + 0], xv.x, s);
            s = fmaf(wreg[i4 * 4 + 1], xv.y, s);
            s = fmaf(wreg[i4 * 4 + 2], xv.z, s);
            s = fmaf(wreg[i4 * 4 + 3], xv.w, s);
        }
        s = fmaxf(s + bc, 0.f);
        Xb[(size_t)(blockIdx.x * 16 + row) * 64 + c] = f2bf(s);
    }
}

// ------- layers 2,3 FUSED: aggregate (4 nodes/wave) + K=256 MFMA GEMM ------
// (R11-proven 4-deep form.) A block's 16 aggregated nodes = one GEMM
// row-tile in LDS; wave wv computes column-tile ct=wv with 8 MFMAs;
// W-frags from L2-resident wfrag. Value flow identical to verified gemm256.

template <bool F32OUT>
__global__ __launch_bounds__(256) void agg_gemm(
    const ushortx* __restrict__ Xb, const float* __restrict__ ALS,
    const float* __restrict__ ALD, const int* __restrict__ off,
    const int* __restrict__ csr_src, const ushortx* __restrict__ wfrag,
    const float* __restrict__ bias, ushortx* __restrict__ XbOut,
    float* __restrict__ OUTF) {
    __shared__ float4 wtab4[4][4][21];   // [wave][group][slot pad21]
    __shared__ int    svtab[4][4][21];
    __shared__ ushortx sAgg[16][264];    // 16 rows x 528B pitch (8.25 KB)
    const int wv = threadIdx.x >> 6;
    const int l = threadIdx.x & 63;
    const int g = l >> 4, c4 = l & 15;
    const int node = blockIdx.x * 16 + wv * 4 + g;
    const int beg = off[node], end = off[node + 1];
    int md = end - beg;
    md = max(md, __shfl_xor(md, 16, 64));
    md = max(md, __shfl_xor(md, 32, 64));
    const float4 aldv = ((const float4*)ALD)[node];
    const uint2* xb2 = (const uint2*)Xb;   // row = 16 uint2 (64 bf16)
    const float4* wt = &wtab4[wv][g][0];
    const int* st = &svtab[wv][g][0];
    float4 a0 = {0.f, 0.f, 0.f, 0.f};      // head 0, ch c4*4..+3
    float4 a1 = {0.f, 0.f, 0.f, 0.f};
    float4 a2 = {0.f, 0.f, 0.f, 0.f};
    float4 a3 = {0.f, 0.f, 0.f, 0.f};
    float4 den4 = {0.f, 0.f, 0.f, 0.f};

#define UPD(uu, ww)                                                 \
    {                                                               \
        float c0v = __uint_as_float((uu).x << 16);                  \
        float c1v = __uint_as_float((uu).x & 0xFFFF0000u);          \
        float c2v = __uint_as_float((uu).y << 16);                  \
        float c3v = __uint_as_float((uu).y & 0xFFFF0000u);          \
        a0.x = fmaf((ww).x, c0v, a0.x); a0.y = fmaf((ww).x, c1v, a0.y); \
        a0.z = fmaf((ww).x, c2v, a0.z); a0.w = fmaf((ww).x, c3v, a0.w); \
        a1.x = fmaf((ww).y, c0v, a1.x); a1.y = fmaf((ww).y, c1v, a1.y); \
        a1.z = fmaf((ww).y, c2v, a1.z); a1.w = fmaf((ww).y, c3v, a1.w); \
        a2.x = fmaf((ww).z, c0v, a2.x); a2.y = fmaf((ww).z, c1v, a2.y); \
        a2.z = fmaf((ww).z, c2v, a2.z); a2.w = fmaf((ww).z, c3v, a2.w); \
        a3.x = fmaf((ww).w, c0v, a3.x); a3.y = fmaf((ww).w, c1v, a3.y); \
        a3.z = fmaf((ww).w, c2v, a3.z); a3.w = fmaf((ww).w, c3v, a3.w); \
    }

    for (int c0 = 0; c0 < md; c0 += 16) {
        const int jj = beg + c0 + c4;
        int sv = 0;
        float4 w4 = {0.f, 0.f, 0.f, 0.f};
        if (jj < end) {
            sv = csr_src[jj];
            w4 = edge_w4(((const float4*)ALS)[sv], aldv);
        }
        den4.x += w4.x; den4.y += w4.y; den4.z += w4.z; den4.w += w4.w;
        wtab4[wv][g][c4] = w4;
        svtab[wv][g][c4] = sv;
        __builtin_amdgcn_wave_barrier();
        asm volatile("s_waitcnt lgkmcnt(0)" ::: "memory");
        __builtin_amdgcn_sched_barrier(0);

        const int mc = min(16, md - c0);
        for (int t = 0; t < mc; t += 4) {
            float4 wA = wt[t + 0]; int sA = st[t + 0];
            float4 wB = wt[t + 1]; int sB = st[t + 1];
            float4 wC = wt[t + 2]; int sC = st[t + 2];
            float4 wD = wt[t + 3]; int sD = st[t + 3];
            uint2 uA = xb2[(size_t)sA * 16 + c4];
            uint2 uB = xb2[(size_t)sB * 16 + c4];
            uint2 uC = xb2[(size_t)sC * 16 + c4];
            uint2 uD = xb2[(size_t)sD * 16 + c4];
            UPD(uA, wA);
            UPD(uB, wB);
            UPD(uC, wC);
            UPD(uD, wD);
        }
        __builtin_amdgcn_wave_barrier();
    }
#undef UPD

#pragma unroll
    for (int m = 1; m <= 8; m <<= 1) {
        den4.x += __shfl_xor(den4.x, m, 64);
        den4.y += __shfl_xor(den4.y, m, 64);
        den4.z += __shfl_xor(den4.z, m, 64);
        den4.w += __shfl_xor(den4.w, m, 64);
    }
    {
        float i0 = 1.f / (den4.x + 1e-16f);
        float i1 = 1.f / (den4.y + 1e-16f);
        float i2 = 1.f / (den4.z + 1e-16f);
        float i3 = 1.f / (den4.w + 1e-16f);
        ushortx* orow = &sAgg[wv * 4 + g][0];
        uint p0, p1;
        p0 = (uint)f2bf(a0.x * i0) | ((uint)f2bf(a0.y * i0) << 16);
        p1 = (uint)f2bf(a0.z * i0) | ((uint)f2bf(a0.w * i0) << 16);
        *(uint2*)&orow[0 * 64 + c4 * 4] = uint2{p0, p1};
        p0 = (uint)f2bf(a1.x * i1) | ((uint)f2bf(a1.y * i1) << 16);
        p1 = (uint)f2bf(a1.z * i1) | ((uint)f2bf(a1.w * i1) << 16);
        *(uint2*)&orow[1 * 64 + c4 * 4] = uint2{p0, p1};
        p0 = (uint)f2bf(a2.x * i2) | ((uint)f2bf(a2.y * i2) << 16);
        p1 = (uint)f2bf(a2.z * i2) | ((uint)f2bf(a2.w * i2) << 16);
        *(uint2*)&orow[2 * 64 + c4 * 4] = uint2{p0, p1};
        p0 = (uint)f2bf(a3.x * i3) | ((uint)f2bf(a3.y * i3) << 16);
        p1 = (uint)f2bf(a3.z * i3) | ((uint)f2bf(a3.w * i3) << 16);
        *(uint2*)&orow[3 * 64 + c4 * 4] = uint2{p0, p1};
    }
    __syncthreads();

    // ---- MFMA phase: wave wv computes column-tile ct = wv ----
    const int n = l & 15, q = l >> 4;
    f32x4 acc = {0.f, 0.f, 0.f, 0.f};
#pragma unroll
    for (int kb = 0; kb < 8; ++kb) {
        short8 a = *(const short8*)&sAgg[n][kb * 32 + q * 8];
        short8 b = *(const short8*)&wfrag[(size_t)((wv * 8 + kb) * 64 + l) * 8];
        acc = __builtin_amdgcn_mfma_f32_16x16x32_bf16(b, a, acc, 0, 0, 0);
    }
    const int row = blockIdx.x * 16 + n;
    const int col = wv * 16 + q * 4;
    float4 b4 = ((const float4*)bias)[wv * 4 + q];
    float o0 = fmaxf(acc[0] + b4.x, 0.f);
    float o1 = fmaxf(acc[1] + b4.y, 0.f);
    float o2 = fmaxf(acc[2] + b4.z, 0.f);
    float o3 = fmaxf(acc[3] + b4.w, 0.f);
    if constexpr (F32OUT) {
        float4 ov = {o0, o1, o2, o3};
        *(float4*)&OUTF[(size_t)row * 64 + col] = ov;
    } else {
        uint p0 = (uint)f2bf(o0) | ((uint)f2bf(o1) << 16);
        uint p1 = (uint)f2bf(o2) | ((uint)f2bf(o3) << 16);
        uint2 ov = {p0, p1};
        *(uint2*)&XbOut[(size_t)row * 64 + col] = ov;
    }
}

// ---------------- graph mean-pool + final linear (no atomics) --------------

__global__ __launch_bounds__(256) void pool_graph(
    const float* __restrict__ OUTF, const int* __restrict__ batch,
    const float* __restrict__ lw, const float* __restrict__ lb,
    float* __restrict__ out) {
    const int g = blockIdx.x * 4 + (threadIdx.x >> 6);
    const int l = threadIdx.x & 63;
    if (g >= GG) return;
    int lo = 0, hi = NN;
    while (lo < hi) { int mid = (lo + hi) >> 1; if (batch[mid] < g) lo = mid + 1; else hi = mid; }
    int lo2 = lo, hi2 = NN;
    while (lo2 < hi2) { int mid = (lo2 + hi2) >> 1; if (batch[mid] < g + 1) lo2 = mid + 1; else hi2 = mid; }
    float s = 0.f;
    int nn = lo;
    for (; nn + 4 <= lo2; nn += 4) {
        float a0 = OUTF[(size_t)(nn + 0) * 64 + l];
        float a1 = OUTF[(size_t)(nn + 1) * 64 + l];
        float a2 = OUTF[(size_t)(nn + 2) * 64 + l];
        float a3 = OUTF[(size_t)(nn + 3) * 64 + l];
        s += (a0 + a1) + (a2 + a3);
    }
    for (; nn < lo2; ++nn) s += OUTF[(size_t)nn * 64 + l];
    const float cntf = fmaxf((float)(lo2 - lo), 1.f);
    float v = s / cntf * lw[l];
#pragma unroll
    for (int m = 32; m; m >>= 1) v += __shfl_xor(v, m, 64);
    if (l == 0) out[g] = v + lb[0];
}

// ---------------- launch ----------------

extern "C" void kernel_launch(void* const* d_in, const int* in_sizes, int n_in,
                              void* d_out, int out_size, void* d_ws, size_t ws_size,
                              hipStream_t stream) {
    const float* x     = (const float*)d_in[0];
    const int*   ei    = (const int*)d_in[1];
    const int*   batch = (const int*)d_in[2];
    const float* W1  = (const float*)d_in[3];
    const float* as1 = (const float*)d_in[4];
    const float* ad1 = (const float*)d_in[5];
    const float* b1  = (const float*)d_in[6];
    const float* W2  = (const float*)d_in[7];
    const float* as2 = (const float*)d_in[8];
    const float* ad2 = (const float*)d_in[9];
    const float* b2  = (const float*)d_in[10];
    const float* W3  = (const float*)d_in[11];
    const float* as3 = (const float*)d_in[12];
    const float* ad3 = (const float*)d_in[13];
    const float* b3  = (const float*)d_in[14];
    const float* lw  = (const float*)d_in[15];
    const float* lb  = (const float*)d_in[16];
    float* out = (float*)d_out;

    char* p = (char*)d_ws;
    auto carve = [&](size_t bytes) -> void* {
        void* r = (void*)p;
        p += (bytes + 255) & ~(size_t)255;
        return r;
    };
    int*     off    = (int*)carve((NN + 4) * sizeof(int));
    int*     deg    = (int*)carve(NN * sizeof(int));
    int*     rank   = (int*)carve((size_t)(EE + NN) * sizeof(int));
    int*     bsum   = (int*)carve(NB * sizeof(int));
    int*     boff   = (int*)carve(NB * sizeof(int));
    int*     csr    = (int*)carve((size_t)(EE + NN) * sizeof(int));
    ushortx* xb1    = (ushortx*)carve((size_t)NN * 64 * sizeof(ushortx));   // 12.8 MB
    ushortx* xb2    = (ushortx*)carve((size_t)NN * 64 * sizeof(ushortx));   // 12.8 MB
    float*   outf   = (float*)carve((size_t)NN * 64 * sizeof(float));       // 25.6 MB
    float*   als    = (float*)carve((size_t)NN * 4 * sizeof(float));
    float*   ald    = (float*)carve((size_t)NN * 4 * sizeof(float));
    float*   va1    = (float*)carve(9 * 8 * sizeof(float));
    float*   va2    = (float*)carve(64 * 8 * sizeof(float));
    float*   va3    = (float*)carve(64 * 8 * sizeof(float));
    ushortx* wf2    = (ushortx*)carve(16384 * sizeof(ushortx));
    ushortx* wf3    = (ushortx*)carve(16384 * sizeof(ushortx));

    hipMemsetAsync(deg, 0, NN * sizeof(int), stream);

    const int etot = EE + NN;
    const int eblocks = (etot + 255) / 256;
    hist_kernel<<<eblocks, 256, 0, stream>>>(ei, deg, rank);
    scan_blk<<<NB, 256, 0, stream>>>(deg, bsum);
    scan_mid<<<1, 128, 0, stream>>>(bsum, boff, off);
    scan_fin<<<NB, 256, 0, stream>>>(deg, boff, off);
    fill_sharded<<<2048, 256, 0, stream>>>(ei, off, rank, csr);

    prep_all<<<133, 256, 0, stream>>>(W1, as1, ad1, W2, as2, ad2, W3, as3, ad3,
                                      va1, va2, va3, wf2, wf3);

    const int ablocks = NN / 16;           // 6250: 4 nodes/wave, 4 waves/block
    const int nblocks = (NN + 255) / 256;

    // layer 1 (fused fp32 aggregate + K=36 GEMM)
    att_gemv<9><<<nblocks, 256, 0, stream>>>(x, va1, als, ald);
    agg_gemm1<<<ablocks, 256, 0, stream>>>(x, als, ald, off, csr, W1, b1, xb1);

    // layer 2 (fused aggregate + MFMA GEMM)
    att_gemv_b<<<nblocks, 256, 0, stream>>>(xb1, va2, als, ald);
    agg_gemm<false><<<ablocks, 256, 0, stream>>>(xb1, als, ald, off, csr, wf2,
                                                 b2, xb2, nullptr);

    // layer 3 (fused; fp32 node outputs, pooling in dedicated kernel)
    att_gemv_b<<<nblocks, 256, 0, stream>>>(xb2, va3, als, ald);
    agg_gemm<true><<<ablocks, 256, 0, stream>>>(xb2, als, ald, off, csr, wf3,
                                                b3, nullptr, outf);

    pool_graph<<<(GG + 3) / 4, 256, 0, stream>>>(outf, batch, lw, lb, out);
}